// Round 13
// baseline (352.701 us; speedup 1.0000x reference)
//
#include <hip/hip_runtime.h>
#include <stdint.h>

// Problem constants
#define B_ 4
#define S_ 2048
#define E_ 1024
#define H_ 16
#define HD_ 64

typedef __attribute__((ext_vector_type(8))) short bf16x8;    // 8 bf16 = 4 VGPRs (MFMA A/B frag)
typedef __attribute__((ext_vector_type(4))) float f32x4;     // 16x16 MFMA C/D frag
typedef __attribute__((ext_vector_type(16))) float f32x16;   // 32x32 MFMA C/D frag

__device__ __forceinline__ ushort f2b(float f) {
    union { float f; uint32_t u; } c; c.f = f;
    return (ushort)((c.u + 0x8000u) >> 16);   // round-to-nearest (ties up)
}

// truncating pack: two f32 -> {bf16_trunc(a) lo, bf16_trunc(b) hi} in ONE v_perm.
// Used ONLY for P in attn: the same truncated P feeds numerator (PV) and
// denominator (ones-MFMA), so the <=2^-8 truncation bias cancels in the ratio.
__device__ __forceinline__ uint32_t pkbf_t(float a, float b) {
    union { float f; uint32_t u; } ca, cb; ca.f = a; cb.f = b;
#if __has_builtin(__builtin_amdgcn_perm)
    return __builtin_amdgcn_perm(cb.u, ca.u, 0x07060302u);
#else
    return (ca.u >> 16) | (cb.u & 0xFFFF0000u);
#endif
}

// all-ones iff bit `pos` of wn is set (1 op: v_bfe_i32)
__device__ __forceinline__ uint32_t keepmask(uint32_t wn, int pos) {
#if __has_builtin(__builtin_amdgcn_sbfe)
    return (uint32_t)__builtin_amdgcn_sbfe((int)wn, pos, 1);
#else
    return (uint32_t)(((int32_t)(wn << (31 - pos))) >> 31);
#endif
}

#if __has_builtin(__builtin_amdgcn_exp2f)
#define EXP2(x) __builtin_amdgcn_exp2f(x)
#else
#define EXP2(x) exp2f(x)
#endif

// async global->LDS, 16B per lane; LDS dest = wave-uniform base + lane*16,
// global src = PER-LANE address (gather) -> source-side permutations are free.
__device__ __forceinline__ void gl2lds16(const ushort* g, const ushort* l) {
    __builtin_amdgcn_global_load_lds(
        (const __attribute__((address_space(1))) unsigned int*)g,
        (__attribute__((address_space(3))) unsigned int*)l,
        16, 0, 0);
}

// ---------------------------------------------------------------- fused converts
__global__ __launch_bounds__(256) void cvt_all(
    const float* __restrict__ x, const float* __restrict__ wq, const float* __restrict__ wo,
    ushort* __restrict__ xb, ushort* __restrict__ wqb, ushort* __restrict__ wob) {
    int i = blockIdx.x * 256 + threadIdx.x;
    const float* src; ushort* dst; int off;
    if (i < 2097152)      { src = x;  dst = xb;  off = i; }
    else if (i < 2883584) { src = wq; dst = wqb; off = i - 2097152; }
    else                  { src = wo; dst = wob; off = i - 2883584; }
    float4 f = ((const float4*)src)[off];
    ushort4 o;
    o.x = f2b(f.x); o.y = f2b(f.y); o.z = f2b(f.z); o.w = f2b(f.w);
    ((ushort4*)dst)[off] = o;
}

// mask [B,S,S] int32 (0/1) -> bit-packed, kt-major:
// mb[((b*32 + kt)*2048 + q)*2 + w] bit c = mask[b][q][kt*64 + w*32 + c]
__global__ __launch_bounds__(256) void pack_mask(const int* __restrict__ mask,
                                                 uint32_t* __restrict__ mb) {
    int i = blockIdx.x * 256 + threadIdx.x;   // 16777216 threads
    unsigned long long bal = __ballot(mask[i] == 1);
    int lane = threadIdx.x & 63;
    if (lane < 2) {
        int b = i >> 22, q = (i >> 11) & 2047, c = i & 2047;
        int kt = c >> 6;
        mb[((uint64_t)(b * 32 + kt) * 2048 + q) * 2 + lane] =
            (lane == 0) ? (uint32_t)bal : (uint32_t)(bal >> 32);
    }
}

// ---------------------------------------------------------------- GEMM core (dist-2 ring, 32x32x16, T2-swizzled LDS)
// Validated round 10: swizzle dropped SQ_LDS_BANK_CONFLICT (qkv fell out of
// top-5, 96.4 -> <92.6 us). Unchanged.
template <int KD>
__device__ __forceinline__ void gemm_bt_core(
    const ushort* __restrict__ A, const ushort* __restrict__ Bm,
    int m0, int n0, ushort* L, f32x16 (&acc)[2][2])
{
    constexpr int NST = KD / 32;
    const int tid  = threadIdx.x;
    const int lane = tid & 63;
    const int wave = tid >> 6;
    const int wm = wave >> 1, wn = wave & 1;
    const int fr = lane & 31;            // row/col within 32x32 tile
    const int fq = lane >> 5;            // k-half selector
    const int fsw = (lane >> 1) & 3;     // row bits 1-2 (read-side swizzle)
    const int lrow = lane >> 2;
    const int lk   = (((lane & 3) ^ ((lane >> 3) & 3)) * 8);  // swizzled source k-chunk

#pragma unroll
    for (int i = 0; i < 2; ++i)
#pragma unroll
        for (int j = 0; j < 2; ++j)
#pragma unroll
            for (int e = 0; e < 16; ++e) acc[i][j][e] = 0.f;

    ushort* s0 = L;
    ushort* s1 = L + 8192;
    ushort* s2 = L + 16384;

    const uint64_t arow = (uint64_t)(m0 + lrow) * KD + lk;
    const uint64_t brow = (uint64_t)(n0 + lrow) * KD + lk;

#define GEMM_STAGE(k0, slot)                                                     \
    {                                                                            \
        _Pragma("unroll")                                                        \
        for (int t = 0; t < 2; ++t) {                                            \
            const int r0 = t * 64 + wave * 16;                                   \
            gl2lds16(&A [arow + (uint64_t)r0 * KD + (k0)], &(slot)[r0 * 32]);    \
            gl2lds16(&Bm[brow + (uint64_t)r0 * KD + (k0)], &(slot)[4096 + r0 * 32]); \
        }                                                                        \
    }

    GEMM_STAGE(0, s0);
    GEMM_STAGE(32, s1);
    asm volatile("s_waitcnt vmcnt(4)" ::: "memory");
    __builtin_amdgcn_s_barrier();
    __builtin_amdgcn_sched_barrier(0);

    ushort* cur = s0; ushort* nxt = s1; ushort* tgt = s2;

    for (int kt = 0; kt < NST; ++kt) {
        if (kt < NST - 2) GEMM_STAGE((kt + 2) * 32, tgt);

        bf16x8 af[2][2], bfr[2][2];      // [tile i|j][k-subtile s]
#pragma unroll
        for (int i = 0; i < 2; ++i)
#pragma unroll
            for (int s = 0; s < 2; ++s)
                af[i][s] = *(const bf16x8*)&cur[(wm * 64 + i * 32 + fr) * 32 +
                                                 (((s * 2 + fq) ^ fsw) * 8)];
#pragma unroll
        for (int j = 0; j < 2; ++j)
#pragma unroll
            for (int s = 0; s < 2; ++s)
                bfr[j][s] = *(const bf16x8*)&cur[4096 + (wn * 64 + j * 32 + fr) * 32 +
                                                  (((s * 2 + fq) ^ fsw) * 8)];
        __builtin_amdgcn_s_setprio(1);
#pragma unroll
        for (int s = 0; s < 2; ++s)
#pragma unroll
            for (int i = 0; i < 2; ++i)
#pragma unroll
                for (int j = 0; j < 2; ++j)
                    acc[i][j] = __builtin_amdgcn_mfma_f32_32x32x16_bf16(
                        af[i][s], bfr[j][s], acc[i][j], 0, 0, 0);
        __builtin_amdgcn_s_setprio(0);

        if (kt < NST - 2) {
            asm volatile("s_waitcnt vmcnt(4)" ::: "memory");
        } else {
            asm volatile("s_waitcnt vmcnt(0)" ::: "memory");
        }
        __builtin_amdgcn_s_barrier();
        __builtin_amdgcn_sched_barrier(0);

        ushort* o = cur; cur = nxt; nxt = tgt; tgt = o;
    }
#undef GEMM_STAGE
}

// ---------------------------------------------------------------- QKV GEMM
// A-reuse block order (round 13): within each XCD (3 n-panels x 64 m-tiles),
// iterate 8 m-groups x {3 n-panels x 8 m-tiles}. The 8-m-tile A chunk (2 MB)
// stays L2-resident (4 MB/XCD) across its 3 n-visits -> A fetched ONCE per XCD
// (was 3x: R9 FETCH=200MB, A re-read 384MB was the qkv bottleneck).
__global__ __launch_bounds__(256) void qkv_gemm(
    const ushort* __restrict__ xb, const ushort* __restrict__ wb,
    const float* __restrict__ bqkv,
    ushort* __restrict__ qo, ushort* __restrict__ ko, ushort* __restrict__ vto)
{
    __shared__ __align__(16) ushort L[24576];   // 48 KB ring
    f32x16 acc[2][2];
    const int lin = blockIdx.x;                  // 1536 = 8 XCD * 192
    const int xcd = lin & 7;
    const int idx = lin >> 3;                    // 0..191
    const int g   = idx / 24;                    // 8 m-groups of 8
    const int r   = idx % 24;
    const int n_l = r >> 3;                      // 3 n-panels per XCD
    const int m_l = r & 7;
    const int m0 = (g * 8 + m_l) * 128;
    const int n0 = (xcd * 3 + n_l) * 128;
    gemm_bt_core<1024>(xb, wb, m0, n0, L, acc);

    const int lane = threadIdx.x & 63, wave = threadIdx.x >> 6;
    const int wm = wave >> 1, wn = wave & 1;
    const int ls = lane >> 5;                    // k-group half
    const float QSC = 0.125f * 1.4426950408889634f;
#pragma unroll
    for (int j = 0; j < 2; ++j) {
        const int n = n0 + wn * 64 + j * 32 + (lane & 31);
        const int h = n / 192, f = n % 192;
        const float bias = bqkv[n];
#pragma unroll
        for (int i2 = 0; i2 < 2; ++i2) {
#pragma unroll
            for (int q = 0; q < 4; ++q) {
                const int mbase = m0 + wm * 64 + i2 * 32 + q * 8 + ls * 4;
                if (f < 128) {
#pragma unroll
                    for (int v = 0; v < 4; ++v) {
                        const int m = mbase + v;
                        const int b = m >> 11, s = m & 2047;
                        const float val = acc[i2][j][q * 4 + v] + bias;
                        if (f < 64) qo[((uint64_t)(b * 16 + h) * 2048 + s) * 64 + f]        = f2b(val * QSC);
                        else        ko[((uint64_t)(b * 16 + h) * 2048 + s) * 64 + (f - 64)] = f2b(val);
                    }
                } else {
                    const int b = mbase >> 11, s = mbase & 2047;
                    ushort4 pk;
                    pk.x = f2b(acc[i2][j][q * 4 + 0] + bias);
                    pk.y = f2b(acc[i2][j][q * 4 + 1] + bias);
                    pk.z = f2b(acc[i2][j][q * 4 + 2] + bias);
                    pk.w = f2b(acc[i2][j][q * 4 + 3] + bias);
                    *(ushort4*)&vto[((uint64_t)(b * 16 + h) * 64 + (f - 128)) * 2048 + s] = pk;
                }
            }
        }
    }
}

// ---------------------------------------------------------------- flash attention v13
// (validated round 12: 91.0 us, no spill; kept. attn has hit ~91 across three
//  structures -- MFMA busy ~32us vs 29us FLOP floor; low-yield to push more.)
__global__ __launch_bounds__(256, 2) void attn_kernel(
    const ushort* __restrict__ qa, const ushort* __restrict__ ka,
    const ushort* __restrict__ vta, const uint32_t* __restrict__ mbits,
    ushort* __restrict__ ctxo)
{
    __shared__ __align__(16) ushort LDSH[24576];   // 48 KB: 3 x (K 8KB + V 8KB)
    ushort* const Ks0 = LDSH;
    ushort* const Vt0 = LDSH + 4096;
    ushort* const Ks1 = LDSH + 8192;
    ushort* const Vt1 = LDSH + 12288;
    ushort* const Ks2 = LDSH + 16384;
    ushort* const Vt2 = LDSH + 20480;
    ushort* const CTX = LDSH;                      // 32 KB epilogue stage (all slots dead)

    // bijective XCD swizzle for 512 = 8 XCDs x (8 bh x 8 qb)
    const int bid = blockIdx.x;
    const int bh = (bid & 7) * 8 + (bid >> 6);
    const int qb = (bid >> 3) & 7;                 // 256-row q-block
    const int b = bh >> 4;
    const int tid = threadIdx.x, lane = tid & 63, wave = tid >> 6;
    const int col = lane & 15, rg = lane >> 4;

    const uint64_t bhoff = (uint64_t)bh * (S_ * 64);
    const ushort* qp = qa + bhoff + (uint64_t)qb * 256 * 64;
    const ushort* kp = ka + bhoff;
    const ushort* vp = vta + bhoff;                       // [64][2048]
    // mask words for this thread's 4 q-rows (i=0..3 -> +i*32 words)
    const uint32_t* mkb = mbits + ((uint64_t)(b * 32) * 2048 + qb * 256 + wave * 64 + col) * 2;

    const int lr = lane >> 3;
    const int usw = (lane & 7) ^ lr;
    const int r0s = wave * 16 + lr;
    const int r1s = r0s + 8;
    const int sg0 = (r0s & 32) | ((r0s & 12) << 1) | ((r0s & 16) >> 2) | (r0s & 3);
    const int sg1 = (r1s & 32) | ((r1s & 12) << 1) | ((r1s & 16) >> 2) | (r1s & 3);
    const int kb0 = sg0 * 64 + usw * 8;
    const int kb1 = sg1 * 64 + usw * 8;
    const int vb0 = r0s * 2048 + usw * 8;
    const int vb1 = r1s * 2048 + usw * 8;
    const int ldst0 = wave * 1024;
    const int ldst1 = ldst0 + 512;

    // Q fragments straight from global (4 x 16 q-rows per wave)
    bf16x8 aq[4][2];
#pragma unroll
    for (int i = 0; i < 4; ++i)
#pragma unroll
        for (int k2 = 0; k2 < 2; ++k2)
            aq[i][k2] = *(const bf16x8*)&qp[(wave * 64 + i * 16 + col) * 64 + k2 * 32 + rg * 8];

    gl2lds16(&kp[kb0], &Ks0[ldst0]);
    gl2lds16(&kp[kb1], &Ks0[ldst1]);
    gl2lds16(&vp[vb0], &Vt0[ldst0]);
    gl2lds16(&vp[vb1], &Vt0[ldst1]);
    gl2lds16(&kp[4096 + kb0], &Ks1[ldst0]);
    gl2lds16(&kp[4096 + kb1], &Ks1[ldst1]);
    gl2lds16(&vp[vb0 + 64], &Vt1[ldst0]);
    gl2lds16(&vp[vb1 + 64], &Vt1[ldst1]);
    uint2 m_cur[4], m_nxt[4], m_new[4];
#pragma unroll
    for (int i = 0; i < 4; ++i) {
        m_cur[i] = *(const uint2*)(mkb + i * 32);
        m_nxt[i] = *(const uint2*)(mkb + 4096 + i * 32);
        m_new[i] = m_nxt[i];
    }
    asm volatile("s_waitcnt vmcnt(0)" ::: "memory");
    __builtin_amdgcn_s_barrier();
    __builtin_amdgcn_sched_barrier(0);

    const f32x4 fz = {0.f, 0.f, 0.f, 0.f};
    f32x4 acc[4][4];                      // ctx^T: [dt][i]
#pragma unroll
    for (int dt = 0; dt < 4; ++dt)
#pragma unroll
        for (int i = 0; i < 4; ++i) acc[dt][i] = fz;
    f32x4 acc5[4] = {fz, fz, fz, fz};

    bf16x8 vone;
#pragma unroll
    for (int e = 0; e < 8; ++e) vone[e] = (short)0x3F80;

    int bpos[2][4];
#pragma unroll
    for (int p = 0; p < 2; ++p)
#pragma unroll
        for (int v = 0; v < 4; ++v) bpos[p][v] = rg * 8 + p * 4 + v;

    const int u0 = (rg ^ (col & 7)) << 3;

    const ushort* cK = Ks0; const ushort* cV = Vt0;
    const ushort* nK = Ks1; const ushort* nV = Vt1;
    ushort* tK = Ks2; ushort* tV = Vt2;

    for (int kt = 0; kt < 32; ++kt) {
        // prefetch kt+2 (distance 2): 4 gl2lds + 4 mask loads = 8 vmem ops
        if (kt < 30) {
            const int k2 = (kt + 2) * 4096;
            gl2lds16(&kp[k2 + kb0], &tK[ldst0]);
            gl2lds16(&kp[k2 + kb1], &tK[ldst1]);
            gl2lds16(&vp[vb0 + (kt + 2) * 64], &tV[ldst0]);
            gl2lds16(&vp[vb1 + (kt + 2) * 64], &tV[ldst1]);
#pragma unroll
            for (int i = 0; i < 4; ++i)
                m_new[i] = *(const uint2*)(mkb + (uint64_t)(kt + 2) * 4096 + i * 32);
        }

        // scores S^T (log2 domain): 32 MFMA
        f32x4 sc[4][4];
        __builtin_amdgcn_s_setprio(1);
#pragma unroll
        for (int j = 0; j < 4; ++j) {
            bf16x8 bk0 = *(const bf16x8*)&cK[(j * 16 + col) * 64 + u0];
            bf16x8 bk1 = *(const bf16x8*)&cK[(j * 16 + col) * 64 + (u0 ^ 32)];
#pragma unroll
            for (int i = 0; i < 4; ++i) {
                f32x4 z = __builtin_amdgcn_mfma_f32_16x16x32_bf16(bk0, aq[i][0], fz, 0, 0, 0);
                sc[i][j] = __builtin_amdgcn_mfma_f32_16x16x32_bf16(bk1, aq[i][1], z, 0, 0, 0);
            }
        }
        __builtin_amdgcn_s_setprio(0);

        // mask + exp2 (thinned) -> P fragments
        bf16x8 bp[4][2];
#pragma unroll
        for (int i = 0; i < 4; ++i) {
            const uint2 mw = m_cur[i];
            const uint32_t wnx = ~mw.x, wny = ~mw.y;
            union { uint32_t w[4]; bf16x8 v; } p0, p1;
#pragma unroll
            for (int j = 0; j < 4; ++j) {
                const uint32_t wn = (j & 2) ? wny : wnx;
                const int p = j & 1;
                float pe[4];
#pragma unroll
                for (int v = 0; v < 4; ++v) {
                    union { float f; uint32_t u; } cu;
                    cu.f = sc[i][j][v];
                    cu.u &= keepmask(wn, bpos[p][v]);
                    pe[v] = EXP2(cu.f);
                }
                const uint32_t lo = pkbf_t(pe[0], pe[1]);
                const uint32_t hi = pkbf_t(pe[2], pe[3]);
                if (j < 2) { p0.w[p * 2] = lo; p0.w[p * 2 + 1] = hi; }
                else       { p1.w[p * 2] = lo; p1.w[p * 2 + 1] = hi; }
            }
            bp[i][0] = p0.v;
            bp[i][1] = p1.v;
        }

        // PV + denominator: 40 MFMA
        __builtin_amdgcn_s_setprio(1);
#pragma unroll
        for (int i = 0; i < 4; ++i) {
            acc5[i] = __builtin_amdgcn_mfma_f32_16x16x32_bf16(vone, bp[i][0], acc5[i], 0, 0, 0);
            acc5[i] = __builtin_amdgcn_mfma_f32_16x16x32_bf16(vone, bp[i][1], acc5[i], 0, 0, 0);
        }
#pragma unroll
        for (int dt = 0; dt < 4; ++dt) {
            bf16x8 av0 = *(const bf16x8*)&cV[(dt * 16 + col) * 64 + u0];
            bf16x8 av1 = *(const bf16x8*)&cV[(dt * 16 + col) * 64 + (u0 ^ 32)];
#pragma unroll
            for (int i = 0; i < 4; ++i) {
                acc[dt][i] = __builtin_amdgcn_mfma_f32_16x16x32_bf16(av0, bp[i][0], acc[dt][i], 0, 0, 0);
                acc[dt][i] = __builtin_amdgcn_mfma_f32_16x16x32_bf16(av1, bp[i][1], acc[dt][i], 0, 0, 0);
            }
        }
        __builtin_amdgcn_s_setprio(0);

        // counted-vmcnt barrier: keep THIS phase's 8 prefetch ops in flight.
        if (kt < 30) {
            asm volatile("s_waitcnt vmcnt(8)" ::: "memory");
        } else {
            asm volatile("s_waitcnt vmcnt(0)" ::: "memory");
        }
        __builtin_amdgcn_s_barrier();
        __builtin_amdgcn_sched_barrier(0);

        const ushort* oK = cK; const ushort* oV = cV;
        cK = nK; cV = nV; nK = tK; nV = tV; tK = (ushort*)oK; tV = (ushort*)oV;
#pragma unroll
        for (int i = 0; i < 4; ++i) { m_cur[i] = m_nxt[i]; m_nxt[i] = m_new[i]; }
    }

    float linv[4];
#pragma unroll
    for (int i = 0; i < 4; ++i) linv[i] = 1.0f / acc5[i][0];

    // transpose ctx^T through CTX (32 KB, swizzled) for coalesced store
#pragma unroll
    for (int dt = 0; dt < 4; ++dt)
#pragma unroll
        for (int i = 0; i < 4; ++i) {
            const int q = wave * 64 + i * 16 + col;
            const int d = dt * 16 + rg * 4;
            const int gg = (d >> 3) ^ (q & 7);
            ushort4 pk;
            pk.x = f2b(acc[dt][i][0] * linv[i]);
            pk.y = f2b(acc[dt][i][1] * linv[i]);
            pk.z = f2b(acc[dt][i][2] * linv[i]);
            pk.w = f2b(acc[dt][i][3] * linv[i]);
            *(ushort4*)&CTX[q * 64 + gg * 8 + (d & 7)] = pk;
        }
    __syncthreads();
    const int h = bh & 15;
    const uint64_t obase = (uint64_t)(b * S_ + qb * 256) * E_ + (uint64_t)h * 64;
#pragma unroll
    for (int t4 = 0; t4 < 8; ++t4) {
        const int id = tid + t4 * 256;
        const int r = id >> 3, c8 = id & 7;
        *(bf16x8*)&ctxo[obase + (uint64_t)r * E_ + c8 * 8] =
            *(const bf16x8*)&CTX[r * 64 + ((c8 ^ (r & 7)) << 3)];
    }
}

// ---------------------------------------------------------------- output GEMM
// XCD owns one full n-panel (A read once) -- already A-reuse-optimal.
__global__ __launch_bounds__(256) void out_gemm(
    const ushort* __restrict__ ctxb, const ushort* __restrict__ wob,
    const float* __restrict__ bo, float* __restrict__ out)
{
    __shared__ __align__(16) ushort L[24576];   // 48 KB ring
    f32x16 acc[2][2];
    const int lin = blockIdx.x;
    const int swz = (lin & 7) * 64 + (lin >> 3);
    const int m0 = (swz & 63) * 128;
    const int n0 = (swz >> 6) * 128;
    gemm_bt_core<1024>(ctxb, wob, m0, n0, L, acc);

    const int lane = threadIdx.x & 63, wave = threadIdx.x >> 6;
    const int wm = wave >> 1, wn = wave & 1;
    const int ls = lane >> 5;
#pragma unroll
    for (int j = 0; j < 2; ++j) {
        const int n = n0 + wn * 64 + j * 32 + (lane & 31);
        const float bias = bo[n];
#pragma unroll
        for (int i2 = 0; i2 < 2; ++i2) {
#pragma unroll
            for (int q = 0; q < 4; ++q) {
                const int mbase = m0 + wm * 64 + i2 * 32 + q * 8 + ls * 4;
#pragma unroll
                for (int v = 0; v < 4; ++v)
                    out[(uint64_t)(mbase + v) * 1024 + n] = acc[i2][j][q * 4 + v] + bias;
            }
        }
    }
}

// ---------------------------------------------------------------- launch
extern "C" void kernel_launch(void* const* d_in, const int* in_sizes, int n_in,
                              void* d_out, int out_size, void* d_ws, size_t ws_size,
                              hipStream_t stream)
{
    const float* x    = (const float*)d_in[0];
    const int*   mask = (const int*)d_in[1];
    const float* Wqkv = (const float*)d_in[2];
    const float* bqkv = (const float*)d_in[3];
    const float* Wo   = (const float*)d_in[4];
    const float* bo   = (const float*)d_in[5];
    float* out = (float*)d_out;

    char* p = (char*)d_ws;
    ushort* xb  = (ushort*)p; p += (size_t)8388608 * 2;   // x bf16 [8192][1024]
    ushort* wqb = (ushort*)p; p += (size_t)3145728 * 2;   // Wqkv bf16 [3072][1024]
    ushort* wob = (ushort*)p; p += (size_t)1048576 * 2;   // Wo bf16 [1024][1024]
    ushort* qo  = (ushort*)p; p += (size_t)8388608 * 2;   // Q bf16 (log2-domain prescale)
    ushort* ko  = (ushort*)p; p += (size_t)8388608 * 2;   // K bf16 [bh][s][64]
    ushort* vto = (ushort*)p; p += (size_t)8388608 * 2;   // V^T bf16 [bh][64][s]
    ushort* ctx = (ushort*)p; p += (size_t)8388608 * 2;   // ctx bf16 [8192][1024]
    uint32_t* mb = (uint32_t*)p;                          // packed mask bits (kt-major), 2 MB

    cvt_all<<<12288, 256, 0, stream>>>(x, Wqkv, Wo, xb, wqb, wob);
    pack_mask<<<65536, 256, 0, stream>>>(mask, mb);
    qkv_gemm<<<1536, 256, 0, stream>>>(xb, wqb, bqkv, qo, ko, vto);
    attn_kernel<<<512, 256, 0, stream>>>(qo, ko, vto, mb, ctx);
    out_gemm<<<512, 256, 0, stream>>>(ctx, wob, bo, out);
}

// Round 14
// 352.356 us; speedup vs baseline: 1.0010x; 1.0010x over previous
//
#include <hip/hip_runtime.h>
#include <stdint.h>

// Problem constants
#define B_ 4
#define S_ 2048
#define E_ 1024
#define H_ 16
#define HD_ 64

typedef __attribute__((ext_vector_type(8))) short bf16x8;    // 8 bf16 = 4 VGPRs (MFMA A/B frag)
typedef __attribute__((ext_vector_type(4))) float f32x4;     // 16x16 MFMA C/D frag
typedef __attribute__((ext_vector_type(16))) float f32x16;   // 32x32 MFMA C/D frag

__device__ __forceinline__ ushort f2b(float f) {
    union { float f; uint32_t u; } c; c.f = f;
    return (ushort)((c.u + 0x8000u) >> 16);   // round-to-nearest (ties up)
}

// truncating pack: two f32 -> {bf16_trunc(a) lo, bf16_trunc(b) hi} in ONE v_perm.
// Used ONLY for P in attn: the same truncated P feeds numerator (PV) and
// denominator (ones-MFMA), so the <=2^-8 truncation bias cancels in the ratio.
__device__ __forceinline__ uint32_t pkbf_t(float a, float b) {
    union { float f; uint32_t u; } ca, cb; ca.f = a; cb.f = b;
#if __has_builtin(__builtin_amdgcn_perm)
    return __builtin_amdgcn_perm(cb.u, ca.u, 0x07060302u);
#else
    return (ca.u >> 16) | (cb.u & 0xFFFF0000u);
#endif
}

// all-ones iff bit `pos` of wn is set (1 op: v_bfe_i32)
__device__ __forceinline__ uint32_t keepmask(uint32_t wn, int pos) {
#if __has_builtin(__builtin_amdgcn_sbfe)
    return (uint32_t)__builtin_amdgcn_sbfe((int)wn, pos, 1);
#else
    return (uint32_t)(((int32_t)(wn << (31 - pos))) >> 31);
#endif
}

#if __has_builtin(__builtin_amdgcn_exp2f)
#define EXP2(x) __builtin_amdgcn_exp2f(x)
#else
#define EXP2(x) exp2f(x)
#endif

// async global->LDS, 16B per lane; LDS dest = wave-uniform base + lane*16,
// global src = PER-LANE address (gather) -> source-side permutations are free.
__device__ __forceinline__ void gl2lds16(const ushort* g, const ushort* l) {
    __builtin_amdgcn_global_load_lds(
        (const __attribute__((address_space(1))) unsigned int*)g,
        (__attribute__((address_space(3))) unsigned int*)l,
        16, 0, 0);
}

// ---------------------------------------------------------------- fused converts
__global__ __launch_bounds__(256) void cvt_all(
    const float* __restrict__ x, const float* __restrict__ wq, const float* __restrict__ wo,
    ushort* __restrict__ xb, ushort* __restrict__ wqb, ushort* __restrict__ wob) {
    int i = blockIdx.x * 256 + threadIdx.x;
    const float* src; ushort* dst; int off;
    if (i < 2097152)      { src = x;  dst = xb;  off = i; }
    else if (i < 2883584) { src = wq; dst = wqb; off = i - 2097152; }
    else                  { src = wo; dst = wob; off = i - 2883584; }
    float4 f = ((const float4*)src)[off];
    ushort4 o;
    o.x = f2b(f.x); o.y = f2b(f.y); o.z = f2b(f.z); o.w = f2b(f.w);
    ((ushort4*)dst)[off] = o;
}

// mask [B,S,S] int32 (0/1) -> bit-packed, kt-major:
// mb[((b*32 + kt)*2048 + q)*2 + w] bit c = mask[b][q][kt*64 + w*32 + c]
__global__ __launch_bounds__(256) void pack_mask(const int* __restrict__ mask,
                                                 uint32_t* __restrict__ mb) {
    int i = blockIdx.x * 256 + threadIdx.x;   // 16777216 threads
    unsigned long long bal = __ballot(mask[i] == 1);
    int lane = threadIdx.x & 63;
    if (lane < 2) {
        int b = i >> 22, q = (i >> 11) & 2047, c = i & 2047;
        int kt = c >> 6;
        mb[((uint64_t)(b * 32 + kt) * 2048 + q) * 2 + lane] =
            (lane == 0) ? (uint32_t)bal : (uint32_t)(bal >> 32);
    }
}

// ---------------------------------------------------------------- GEMM core (dist-2 ring, 32x32x16, T2-swizzled LDS)
// Validated round 10. Unchanged.
template <int KD>
__device__ __forceinline__ void gemm_bt_core(
    const ushort* __restrict__ A, const ushort* __restrict__ Bm,
    int m0, int n0, ushort* L, f32x16 (&acc)[2][2])
{
    constexpr int NST = KD / 32;
    const int tid  = threadIdx.x;
    const int lane = tid & 63;
    const int wave = tid >> 6;
    const int wm = wave >> 1, wn = wave & 1;
    const int fr = lane & 31;            // row/col within 32x32 tile
    const int fq = lane >> 5;            // k-half selector
    const int fsw = (lane >> 1) & 3;     // row bits 1-2 (read-side swizzle)
    const int lrow = lane >> 2;
    const int lk   = (((lane & 3) ^ ((lane >> 3) & 3)) * 8);  // swizzled source k-chunk

#pragma unroll
    for (int i = 0; i < 2; ++i)
#pragma unroll
        for (int j = 0; j < 2; ++j)
#pragma unroll
            for (int e = 0; e < 16; ++e) acc[i][j][e] = 0.f;

    ushort* s0 = L;
    ushort* s1 = L + 8192;
    ushort* s2 = L + 16384;

    const uint64_t arow = (uint64_t)(m0 + lrow) * KD + lk;
    const uint64_t brow = (uint64_t)(n0 + lrow) * KD + lk;

#define GEMM_STAGE(k0, slot)                                                     \
    {                                                                            \
        _Pragma("unroll")                                                        \
        for (int t = 0; t < 2; ++t) {                                            \
            const int r0 = t * 64 + wave * 16;                                   \
            gl2lds16(&A [arow + (uint64_t)r0 * KD + (k0)], &(slot)[r0 * 32]);    \
            gl2lds16(&Bm[brow + (uint64_t)r0 * KD + (k0)], &(slot)[4096 + r0 * 32]); \
        }                                                                        \
    }

    GEMM_STAGE(0, s0);
    GEMM_STAGE(32, s1);
    asm volatile("s_waitcnt vmcnt(4)" ::: "memory");
    __builtin_amdgcn_s_barrier();
    __builtin_amdgcn_sched_barrier(0);

    ushort* cur = s0; ushort* nxt = s1; ushort* tgt = s2;

    for (int kt = 0; kt < NST; ++kt) {
        if (kt < NST - 2) GEMM_STAGE((kt + 2) * 32, tgt);

        bf16x8 af[2][2], bfr[2][2];      // [tile i|j][k-subtile s]
#pragma unroll
        for (int i = 0; i < 2; ++i)
#pragma unroll
            for (int s = 0; s < 2; ++s)
                af[i][s] = *(const bf16x8*)&cur[(wm * 64 + i * 32 + fr) * 32 +
                                                 (((s * 2 + fq) ^ fsw) * 8)];
#pragma unroll
        for (int j = 0; j < 2; ++j)
#pragma unroll
            for (int s = 0; s < 2; ++s)
                bfr[j][s] = *(const bf16x8*)&cur[4096 + (wn * 64 + j * 32 + fr) * 32 +
                                                  (((s * 2 + fq) ^ fsw) * 8)];
        __builtin_amdgcn_s_setprio(1);
#pragma unroll
        for (int s = 0; s < 2; ++s)
#pragma unroll
            for (int i = 0; i < 2; ++i)
#pragma unroll
                for (int j = 0; j < 2; ++j)
                    acc[i][j] = __builtin_amdgcn_mfma_f32_32x32x16_bf16(
                        af[i][s], bfr[j][s], acc[i][j], 0, 0, 0);
        __builtin_amdgcn_s_setprio(0);

        if (kt < NST - 2) {
            asm volatile("s_waitcnt vmcnt(4)" ::: "memory");
        } else {
            asm volatile("s_waitcnt vmcnt(0)" ::: "memory");
        }
        __builtin_amdgcn_s_barrier();
        __builtin_amdgcn_sched_barrier(0);

        ushort* o = cur; cur = nxt; nxt = tgt; tgt = o;
    }
#undef GEMM_STAGE
}

// ---------------------------------------------------------------- QKV GEMM
// Block order REVERTED to R12's n-major-per-XCD (R13's grouped order spread the
// resident working set past 4MB L2 and cost ~6us).
__global__ __launch_bounds__(256) void qkv_gemm(
    const ushort* __restrict__ xb, const ushort* __restrict__ wb,
    const float* __restrict__ bqkv,
    ushort* __restrict__ qo, ushort* __restrict__ ko, ushort* __restrict__ vto)
{
    __shared__ __align__(16) ushort L[24576];   // 48 KB ring
    f32x16 acc[2][2];
    const int lin = blockIdx.x;                  // 1536 = 8 * 192
    const int swz = (lin & 7) * 192 + (lin >> 3);
    const int m0 = (swz & 63) * 128;
    const int n0 = (swz >> 6) * 128;
    gemm_bt_core<1024>(xb, wb, m0, n0, L, acc);

    const int lane = threadIdx.x & 63, wave = threadIdx.x >> 6;
    const int wm = wave >> 1, wn = wave & 1;
    const int ls = lane >> 5;                    // k-group half
    const float QSC = 0.125f * 1.4426950408889634f;
#pragma unroll
    for (int j = 0; j < 2; ++j) {
        const int n = n0 + wn * 64 + j * 32 + (lane & 31);
        const int h = n / 192, f = n % 192;
        const float bias = bqkv[n];
#pragma unroll
        for (int i2 = 0; i2 < 2; ++i2) {
#pragma unroll
            for (int q = 0; q < 4; ++q) {
                const int mbase = m0 + wm * 64 + i2 * 32 + q * 8 + ls * 4;
                if (f < 128) {
#pragma unroll
                    for (int v = 0; v < 4; ++v) {
                        const int m = mbase + v;
                        const int b = m >> 11, s = m & 2047;
                        const float val = acc[i2][j][q * 4 + v] + bias;
                        if (f < 64) qo[((uint64_t)(b * 16 + h) * 2048 + s) * 64 + f]        = f2b(val * QSC);
                        else        ko[((uint64_t)(b * 16 + h) * 2048 + s) * 64 + (f - 64)] = f2b(val);
                    }
                } else {
                    const int b = mbase >> 11, s = mbase & 2047;
                    ushort4 pk;
                    pk.x = f2b(acc[i2][j][q * 4 + 0] + bias);
                    pk.y = f2b(acc[i2][j][q * 4 + 1] + bias);
                    pk.z = f2b(acc[i2][j][q * 4 + 2] + bias);
                    pk.w = f2b(acc[i2][j][q * 4 + 3] + bias);
                    *(ushort4*)&vto[((uint64_t)(b * 16 + h) * 64 + (f - 128)) * 2048 + s] = pk;
                }
            }
        }
    }
}

// ---------------------------------------------------------------- flash attention v14
// = v13's ring/swizzle/softmax with 8-WAVE blocks (512 threads): each wave owns
//   32 q-rows (v11's per-wave shape, ~70-90 VGPR), QBLK stays 256, grid 512.
//   Waves/CU doubles 8 -> 16 (4/SIMD, launch_bounds(512,4)) -- attn is
//   latency-bound at occ 17%, MFMA floor ~37us vs measured 89.5us.
//   Staging gets cheaper: 512 threads cover a full 64x64 K (or V) tile in ONE
//   gl2lds (thread = 16B unit; row = tid>>3; same XOR/sigma source perm; the
//   wave-base + lane*16 dest lands each unit at the same physical slot as the
//   v13 layout). Per phase: 2 gl2lds + 2 mask loads -> vmcnt(4).
__global__ __launch_bounds__(512, 4) void attn_kernel(
    const ushort* __restrict__ qa, const ushort* __restrict__ ka,
    const ushort* __restrict__ vta, const uint32_t* __restrict__ mbits,
    ushort* __restrict__ ctxo)
{
    __shared__ __align__(16) ushort LDSH[24576];   // 48 KB: 3 x (K 8KB + V 8KB)
    ushort* const Ks0 = LDSH;
    ushort* const Vt0 = LDSH + 4096;
    ushort* const Ks1 = LDSH + 8192;
    ushort* const Vt1 = LDSH + 12288;
    ushort* const Ks2 = LDSH + 16384;
    ushort* const Vt2 = LDSH + 20480;
    ushort* const CTX = LDSH;                      // 32 KB epilogue stage (all slots dead)

    // bijective XCD swizzle for 512 = 8 XCDs x (8 bh x 8 qb)
    const int bid = blockIdx.x;
    const int bh = (bid & 7) * 8 + (bid >> 6);
    const int qb = (bid >> 3) & 7;                 // 256-row q-block
    const int b = bh >> 4;
    const int tid = threadIdx.x, lane = tid & 63, wave = tid >> 6;   // wave 0..7
    const int col = lane & 15, rg = lane >> 4;

    const uint64_t bhoff = (uint64_t)bh * (S_ * 64);
    const ushort* qp = qa + bhoff + (uint64_t)qb * 256 * 64;
    const ushort* kp = ka + bhoff;
    const ushort* vp = vta + bhoff;                       // [64][2048]
    // mask words for this thread's 2 q-rows (i=0,1 -> +i*32 words)
    const uint32_t* mkb = mbits + ((uint64_t)(b * 32) * 2048 + qb * 256 + wave * 32 + col) * 2;

    // staging geometry: thread = one 16B unit of the 64x64 tile
    const int sr  = tid >> 3;                 // source row 0..63
    const int usw = (tid & 7) ^ (sr & 7);     // XOR-swizzled unit
    // sigma(r): bits (k2,jj,rg,v) -> (k2,rg,jj,v)
    const int sg = (sr & 32) | ((sr & 12) << 1) | ((sr & 16) >> 2) | (sr & 3);
    const int kb0 = sg * 64 + usw * 8;        // K source offset (elements)
    const int vb0 = sr * 2048 + usw * 8;      // V source offset (rows natural)
    const int ldst = wave * 512;              // per-wave LDS dst base (elements)

    // Q fragments straight from global (2 x 16 q-rows per wave)
    bf16x8 aq[2][2];
#pragma unroll
    for (int i = 0; i < 2; ++i)
#pragma unroll
        for (int k2 = 0; k2 < 2; ++k2)
            aq[i][k2] = *(const bf16x8*)&qp[(wave * 32 + i * 16 + col) * 64 + k2 * 32 + rg * 8];

    // prologue: K/V[0] -> slot0, K/V[1] -> slot1; masks [0],[1] -> regs
    gl2lds16(&kp[kb0], &Ks0[ldst]);
    gl2lds16(&vp[vb0], &Vt0[ldst]);
    gl2lds16(&kp[4096 + kb0], &Ks1[ldst]);
    gl2lds16(&vp[vb0 + 64], &Vt1[ldst]);
    uint2 m_cur[2], m_nxt[2], m_new[2];
#pragma unroll
    for (int i = 0; i < 2; ++i) {
        m_cur[i] = *(const uint2*)(mkb + i * 32);
        m_nxt[i] = *(const uint2*)(mkb + 4096 + i * 32);
        m_new[i] = m_nxt[i];
    }
    asm volatile("s_waitcnt vmcnt(0)" ::: "memory");
    __builtin_amdgcn_s_barrier();
    __builtin_amdgcn_sched_barrier(0);

    const f32x4 fz = {0.f, 0.f, 0.f, 0.f};
    f32x4 acc[4][2];                      // ctx^T: [dt][i]
#pragma unroll
    for (int dt = 0; dt < 4; ++dt)
#pragma unroll
        for (int i = 0; i < 2; ++i) acc[dt][i] = fz;
    f32x4 acc5[2] = {fz, fz};

    bf16x8 vone;
#pragma unroll
    for (int e = 0; e < 8; ++e) vone[e] = (short)0x3F80;

    int bpos[2][4];
#pragma unroll
    for (int p = 0; p < 2; ++p)
#pragma unroll
        for (int v = 0; v < 4; ++v) bpos[p][v] = rg * 8 + p * 4 + v;

    const int u0 = (rg ^ (col & 7)) << 3;

    const ushort* cK = Ks0; const ushort* cV = Vt0;
    const ushort* nK = Ks1; const ushort* nV = Vt1;
    ushort* tK = Ks2; ushort* tV = Vt2;

    for (int kt = 0; kt < 32; ++kt) {
        // prefetch kt+2 (distance 2): 2 gl2lds + 2 mask loads = 4 vmem ops
        if (kt < 30) {
            gl2lds16(&kp[(kt + 2) * 4096 + kb0], &tK[ldst]);
            gl2lds16(&vp[vb0 + (kt + 2) * 64], &tV[ldst]);
#pragma unroll
            for (int i = 0; i < 2; ++i)
                m_new[i] = *(const uint2*)(mkb + (uint64_t)(kt + 2) * 4096 + i * 32);
        }

        // scores S^T (log2 domain): 16 MFMA / wave
        f32x4 sc[2][4];
        __builtin_amdgcn_s_setprio(1);
#pragma unroll
        for (int j = 0; j < 4; ++j) {
            bf16x8 bk0 = *(const bf16x8*)&cK[(j * 16 + col) * 64 + u0];
            bf16x8 bk1 = *(const bf16x8*)&cK[(j * 16 + col) * 64 + (u0 ^ 32)];
#pragma unroll
            for (int i = 0; i < 2; ++i) {
                f32x4 z = __builtin_amdgcn_mfma_f32_16x16x32_bf16(bk0, aq[i][0], fz, 0, 0, 0);
                sc[i][j] = __builtin_amdgcn_mfma_f32_16x16x32_bf16(bk1, aq[i][1], z, 0, 0, 0);
            }
        }
        __builtin_amdgcn_s_setprio(0);

        // mask + exp2 (thinned) -> P fragments
        bf16x8 bp[2][2];
#pragma unroll
        for (int i = 0; i < 2; ++i) {
            const uint2 mw = m_cur[i];
            const uint32_t wnx = ~mw.x, wny = ~mw.y;
            union { uint32_t w[4]; bf16x8 v; } p0, p1;
#pragma unroll
            for (int j = 0; j < 4; ++j) {
                const uint32_t wn = (j & 2) ? wny : wnx;
                const int p = j & 1;
                float pe[4];
#pragma unroll
                for (int v = 0; v < 4; ++v) {
                    union { float f; uint32_t u; } cu;
                    cu.f = sc[i][j][v];
                    cu.u &= keepmask(wn, bpos[p][v]);
                    pe[v] = EXP2(cu.f);
                }
                const uint32_t lo = pkbf_t(pe[0], pe[1]);
                const uint32_t hi = pkbf_t(pe[2], pe[3]);
                if (j < 2) { p0.w[p * 2] = lo; p0.w[p * 2 + 1] = hi; }
                else       { p1.w[p * 2] = lo; p1.w[p * 2 + 1] = hi; }
            }
            bp[i][0] = p0.v;
            bp[i][1] = p1.v;
        }

        // PV + denominator: 20 MFMA / wave
        __builtin_amdgcn_s_setprio(1);
#pragma unroll
        for (int i = 0; i < 2; ++i) {
            acc5[i] = __builtin_amdgcn_mfma_f32_16x16x32_bf16(vone, bp[i][0], acc5[i], 0, 0, 0);
            acc5[i] = __builtin_amdgcn_mfma_f32_16x16x32_bf16(vone, bp[i][1], acc5[i], 0, 0, 0);
        }
#pragma unroll
        for (int dt = 0; dt < 4; ++dt) {
            bf16x8 av0 = *(const bf16x8*)&cV[(dt * 16 + col) * 64 + u0];
            bf16x8 av1 = *(const bf16x8*)&cV[(dt * 16 + col) * 64 + (u0 ^ 32)];
#pragma unroll
            for (int i = 0; i < 2; ++i) {
                acc[dt][i] = __builtin_amdgcn_mfma_f32_16x16x32_bf16(av0, bp[i][0], acc[dt][i], 0, 0, 0);
                acc[dt][i] = __builtin_amdgcn_mfma_f32_16x16x32_bf16(av1, bp[i][1], acc[dt][i], 0, 0, 0);
            }
        }
        __builtin_amdgcn_s_setprio(0);

        // counted-vmcnt barrier: keep THIS phase's 4 prefetch ops in flight.
        if (kt < 30) {
            asm volatile("s_waitcnt vmcnt(4)" ::: "memory");
        } else {
            asm volatile("s_waitcnt vmcnt(0)" ::: "memory");
        }
        __builtin_amdgcn_s_barrier();
        __builtin_amdgcn_sched_barrier(0);

        const ushort* oK = cK; const ushort* oV = cV;
        cK = nK; cV = nV; nK = tK; nV = tV; tK = (ushort*)oK; tV = (ushort*)oV;
#pragma unroll
        for (int i = 0; i < 2; ++i) { m_cur[i] = m_nxt[i]; m_nxt[i] = m_new[i]; }
    }

    float linv[2];
#pragma unroll
    for (int i = 0; i < 2; ++i) linv[i] = 1.0f / acc5[i][0];

    // transpose ctx^T through CTX (32 KB, swizzled) for coalesced store
#pragma unroll
    for (int dt = 0; dt < 4; ++dt)
#pragma unroll
        for (int i = 0; i < 2; ++i) {
            const int q = wave * 32 + i * 16 + col;
            const int d = dt * 16 + rg * 4;
            const int gg = (d >> 3) ^ (q & 7);
            ushort4 pk;
            pk.x = f2b(acc[dt][i][0] * linv[i]);
            pk.y = f2b(acc[dt][i][1] * linv[i]);
            pk.z = f2b(acc[dt][i][2] * linv[i]);
            pk.w = f2b(acc[dt][i][3] * linv[i]);
            *(ushort4*)&CTX[q * 64 + gg * 8 + (d & 7)] = pk;
        }
    __syncthreads();
    const int h = bh & 15;
    const uint64_t obase = (uint64_t)(b * S_ + qb * 256) * E_ + (uint64_t)h * 64;
#pragma unroll
    for (int t4 = 0; t4 < 4; ++t4) {
        const int id = tid + t4 * 512;
        const int r = id >> 3, c8 = id & 7;
        *(bf16x8*)&ctxo[obase + (uint64_t)r * E_ + c8 * 8] =
            *(const bf16x8*)&CTX[r * 64 + ((c8 ^ (r & 7)) << 3)];
    }
}

// ---------------------------------------------------------------- output GEMM
__global__ __launch_bounds__(256) void out_gemm(
    const ushort* __restrict__ ctxb, const ushort* __restrict__ wob,
    const float* __restrict__ bo, float* __restrict__ out)
{
    __shared__ __align__(16) ushort L[24576];   // 48 KB ring
    f32x16 acc[2][2];
    const int lin = blockIdx.x;
    const int swz = (lin & 7) * 64 + (lin >> 3);
    const int m0 = (swz & 63) * 128;
    const int n0 = (swz >> 6) * 128;
    gemm_bt_core<1024>(ctxb, wob, m0, n0, L, acc);

    const int lane = threadIdx.x & 63, wave = threadIdx.x >> 6;
    const int wm = wave >> 1, wn = wave & 1;
    const int ls = lane >> 5;
#pragma unroll
    for (int j = 0; j < 2; ++j) {
        const int n = n0 + wn * 64 + j * 32 + (lane & 31);
        const float bias = bo[n];
#pragma unroll
        for (int i2 = 0; i2 < 2; ++i2) {
#pragma unroll
            for (int q = 0; q < 4; ++q) {
                const int mbase = m0 + wm * 64 + i2 * 32 + q * 8 + ls * 4;
#pragma unroll
                for (int v = 0; v < 4; ++v)
                    out[(uint64_t)(mbase + v) * 1024 + n] = acc[i2][j][q * 4 + v] + bias;
            }
        }
    }
}

// ---------------------------------------------------------------- launch
extern "C" void kernel_launch(void* const* d_in, const int* in_sizes, int n_in,
                              void* d_out, int out_size, void* d_ws, size_t ws_size,
                              hipStream_t stream)
{
    const float* x    = (const float*)d_in[0];
    const int*   mask = (const int*)d_in[1];
    const float* Wqkv = (const float*)d_in[2];
    const float* bqkv = (const float*)d_in[3];
    const float* Wo   = (const float*)d_in[4];
    const float* bo   = (const float*)d_in[5];
    float* out = (float*)d_out;

    char* p = (char*)d_ws;
    ushort* xb  = (ushort*)p; p += (size_t)8388608 * 2;   // x bf16 [8192][1024]
    ushort* wqb = (ushort*)p; p += (size_t)3145728 * 2;   // Wqkv bf16 [3072][1024]
    ushort* wob = (ushort*)p; p += (size_t)1048576 * 2;   // Wo bf16 [1024][1024]
    ushort* qo  = (ushort*)p; p += (size_t)8388608 * 2;   // Q bf16 (log2-domain prescale)
    ushort* ko  = (ushort*)p; p += (size_t)8388608 * 2;   // K bf16 [bh][s][64]
    ushort* vto = (ushort*)p; p += (size_t)8388608 * 2;   // V^T bf16 [bh][64][s]
    ushort* ctx = (ushort*)p; p += (size_t)8388608 * 2;   // ctx bf16 [8192][1024]
    uint32_t* mb = (uint32_t*)p;                          // packed mask bits (kt-major), 2 MB

    cvt_all<<<12288, 256, 0, stream>>>(x, Wqkv, Wo, xb, wqb, wob);
    pack_mask<<<65536, 256, 0, stream>>>(mask, mb);
    qkv_gemm<<<1536, 256, 0, stream>>>(xb, wqb, bqkv, qo, ko, vto);
    attn_kernel<<<512, 512, 0, stream>>>(qo, ko, vto, mb, ctx);
    out_gemm<<<512, 256, 0, stream>>>(ctx, wob, bo, out);
}